// Round 1
// baseline (225.934 us; speedup 1.0000x reference)
//
#include <hip/hip_runtime.h>
#include <hip/hip_fp16.h>

#define LL 2048
#define BB 2
#define DD 1024
#define HH 16
#define DKK 64

typedef _Float16 h8 __attribute__((ext_vector_type(8)));
typedef _Float16 h4 __attribute__((ext_vector_type(4)));
typedef float f4 __attribute__((ext_vector_type(4)));
typedef float f16v __attribute__((ext_vector_type(16)));

// lgkm-only barrier (keeps prefetch global loads in flight across it)
#define BAR() do {                                              \
    asm volatile("s_waitcnt lgkmcnt(0)" ::: "memory");          \
    __builtin_amdgcn_s_barrier();                               \
    asm volatile("" ::: "memory");                              \
} while (0)

// async global->LDS, 16B per lane; LDS dest is wave-uniform base + lane*16
__device__ __forceinline__ void gload_lds16(const void* g, void* l) {
    __builtin_amdgcn_global_load_lds(
        (const __attribute__((address_space(1))) void*)g,
        (__attribute__((address_space(3))) void*)l, 16, 0, 0);
}

__device__ __forceinline__ unsigned pack2h(float a, float b) {
    union { _Float16 h[2]; unsigned u; } x;
    x.h[0] = (_Float16)a; x.h[1] = (_Float16)b;
    return x.u;
}

// ---------------------------------------------------------------------------
// Kernel 0: convert 7 arrays f32->f16: qin/kin/vin (4M each), wq/wk/wv/wo (1M).
// ---------------------------------------------------------------------------
__global__ __launch_bounds__(256) void cvt_all(
    const float* __restrict__ x0, const float* __restrict__ x1,
    const float* __restrict__ x2, const float* __restrict__ w0,
    const float* __restrict__ w1, const float* __restrict__ w2,
    const float* __restrict__ w3,
    _Float16* __restrict__ y0, _Float16* __restrict__ y1,
    _Float16* __restrict__ y2, _Float16* __restrict__ z0,
    _Float16* __restrict__ z1, _Float16* __restrict__ z2,
    _Float16* __restrict__ z3)
{
    const int sel = blockIdx.y;
    if (sel >= 3 && blockIdx.x >= 512) return;
    const float* src = (sel == 0) ? x0 : (sel == 1) ? x1 : (sel == 2) ? x2
                     : (sel == 3) ? w0 : (sel == 4) ? w1 : (sel == 5) ? w2 : w3;
    _Float16* dst = (sel == 0) ? y0 : (sel == 1) ? y1 : (sel == 2) ? y2
                  : (sel == 3) ? z0 : (sel == 4) ? z1 : (sel == 5) ? z2 : z3;
    const int i = (blockIdx.x * 256 + threadIdx.x) * 8;
    f4 a = *(const f4*)(src + i);
    f4 b = *(const f4*)(src + i + 4);
    h8 o = {(_Float16)a.x, (_Float16)a.y, (_Float16)a.z, (_Float16)a.w,
            (_Float16)b.x, (_Float16)b.y, (_Float16)b.z, (_Float16)b.w};
    *(h8*)(dst + i) = o;
}

// ---------------------------------------------------------------------------
// Kernel 1: QKV projections, m97 structure (global_load_lds + unpadded LDS).
//   mode 0: Q -> qh[head][l][dk] * (0.125 * log2e)   [attn uses exp2]
//   mode 1: K -> kh[head][l][dk]
//   mode 2: V -> vth[head][dk][l]
// ---------------------------------------------------------------------------
__global__ __launch_bounds__(256) void qkv_proj(
    const _Float16* __restrict__ xq, const _Float16* __restrict__ xk,
    const _Float16* __restrict__ xv,
    const _Float16* __restrict__ wq, const float* __restrict__ bq,
    const _Float16* __restrict__ wk, const float* __restrict__ bk,
    const _Float16* __restrict__ wv, const float* __restrict__ bv,
    _Float16* __restrict__ qh, _Float16* __restrict__ kh,
    _Float16* __restrict__ vth)
{
    const int mode = blockIdx.z;
    const _Float16* X    = (mode == 0) ? xq : (mode == 1) ? xk : xv;
    const _Float16* W    = (mode == 0) ? wq : (mode == 1) ? wk : wv;
    const float*    bias = (mode == 0) ? bq : (mode == 1) ? bk : bv;

    __shared__ alignas(16) _Float16 a_sm[128 * 32];
    __shared__ alignas(16) _Float16 b_sm[128 * 32];

    const int tid  = threadIdx.x;
    const int lane = tid & 63;
    const int wave = tid >> 6;
    const int wm = (wave & 1) * 64;
    const int wn = (wave >> 1) * 64;
    const int m0 = blockIdx.x * 128;
    const int n0 = blockIdx.y * 128;

    const int srow = tid >> 2;
    const int scol = (tid & 3) * 8;
    const int lds_base = wave * 512;

    f4 acc[4][4];
    #pragma unroll
    for (int i = 0; i < 4; i++)
        #pragma unroll
        for (int j = 0; j < 4; j++)
            #pragma unroll
            for (int r = 0; r < 4; r++) acc[i][j][r] = 0.f;

    const int fr = lane & 15;
    const int fk = (lane >> 4) * 8;

    for (int k0 = 0; k0 < DD; k0 += 32) {
        gload_lds16(X + (size_t)(m0 + srow) * DD + k0 + scol,       &a_sm[lds_base]);
        gload_lds16(X + (size_t)(m0 + 64 + srow) * DD + k0 + scol,  &a_sm[2048 + lds_base]);
        gload_lds16(W + (size_t)(n0 + srow) * DD + k0 + scol,       &b_sm[lds_base]);
        gload_lds16(W + (size_t)(n0 + 64 + srow) * DD + k0 + scol,  &b_sm[2048 + lds_base]);
        __syncthreads();
        h8 af[4], bfr[4];
        #pragma unroll
        for (int i = 0; i < 4; i++) af[i]  = *(const h8*)&a_sm[(wm + i * 16 + fr) * 32 + fk];
        #pragma unroll
        for (int j = 0; j < 4; j++) bfr[j] = *(const h8*)&b_sm[(wn + j * 16 + fr) * 32 + fk];
        #pragma unroll
        for (int i = 0; i < 4; i++)
            #pragma unroll
            for (int j = 0; j < 4; j++)
                acc[i][j] = __builtin_amdgcn_mfma_f32_16x16x32_f16(af[i], bfr[j], acc[i][j], 0, 0, 0);
        __syncthreads();
    }

    const int colc = lane & 15;
    const int rowb = (lane >> 4) * 4;
    #pragma unroll
    for (int i = 0; i < 4; i++) {
        #pragma unroll
        for (int j = 0; j < 4; j++) {
            const int nn = n0 + wn + j * 16 + colc;
            const float bval = bias[nn];
            #pragma unroll
            for (int reg = 0; reg < 4; reg++) {
                const int mm = m0 + wm + i * 16 + rowb + reg;
                float v = acc[i][j][reg] + bval;
                const int b = mm & 1, l = mm >> 1;
                const int h = nn >> 6, dk = nn & 63;
                const int head = b * HH + h;
                if (mode == 0) {
                    v *= 0.1803368801111243f;  // DK^-0.5 * log2(e)
                    qh[((size_t)head * LL + l) * DKK + dk] = (_Float16)v;
                } else if (mode == 1) {
                    kh[((size_t)head * LL + l) * DKK + dk] = (_Float16)v;
                } else {
                    vth[((size_t)head * DKK + dk) * LL + l] = (_Float16)v;
                }
            }
        }
    }
}

// ---------------------------------------------------------------------------
// Kernel 2: attention v4 — 8-wave blocks, wave pairs split the s-tile.
//   Waves 0-3: q-strip (wave&3), s-subtiles st 0,1 of each 128-s tile.
//   Waves 4-7: same q-strips,    s-subtiles st 2,3.
//   No online max -> partial (O, lsum) combine by pure addition via an LDS
//   exchange at the end (xch overlays k_sm/vt_sm after the last barrier).
//   Occupancy: grid 512 x 512thr = 2 blocks/CU x 8 waves = 16 waves/CU
//   (was 8).  VGPR pressure drops vs v3 (sc[2] not sc[4], half prefetch).
//   XCD swizzle: each XCD owns 4 contiguous heads (2MB K/V fits 4MB L2).
// ---------------------------------------------------------------------------
__global__ __launch_bounds__(512, 4) void attn(
    const _Float16* __restrict__ qh, const _Float16* __restrict__ kh,
    const _Float16* __restrict__ vth, _Float16* __restrict__ oh)
{
    // bijective XCD swizzle: raw linear id rb -> logical lb so that
    // rb%8 (the XCD) selects a contiguous 4-head chunk.
    const int rb = blockIdx.y * 16 + blockIdx.x;     // 0..511
    const int lb = (rb & 7) * 64 + (rb >> 3);        // bijection on [0,512)
    const int head = lb >> 4;
    const int q0   = (lb & 15) * 128;

    const int tid = threadIdx.x, lane = tid & 63, wave = tid >> 6;  // 0..7
    const int qstrip = wave & 3;
    const int sh     = wave >> 2;      // s-half of the tile this wave owns
    const int qw = q0 + qstrip * 32;

    // single shared buffer so the end-of-kernel exchange can overlay k/vt
    __shared__ alignas(16) char smem_raw[128 * 72 * 2 + 64 * 136 * 2 + 4 * 32 * 4];
    _Float16 (*k_sm)[72]   = (_Float16(*)[72])smem_raw;                  // [s][dk] 18432B
    _Float16 (*vt_sm)[136] = (_Float16(*)[136])(smem_raw + 18432);       // [dk][s] 17408B
    float    (*ls_sm)[32]  = (float(*)[32])(smem_raw + 18432 + 17408);   // 512B
    float*   xch           = (float*)smem_raw;                           // 33792B used

    const int rq = lane & 31;
    const int hi = lane >> 5;
    const int kb = hi * 8;
    const int tid8 = tid * 8;          // 0..4088

    const _Float16* khead  = kh  + (size_t)head * LL * DKK;
    const _Float16* vthead = vth + (size_t)head * DKK * LL;

    // Q strip 32x64 -> 4 B-frags: B[n=lane&31][k=hi*8+j]
    const _Float16* qbase = qh + ((size_t)head * LL + qw + rq) * DKK;
    h8 qa[4];
    #pragma unroll
    for (int kf = 0; kf < 4; kf++) qa[kf] = *(const h8*)(qbase + kf * 16 + kb);

    f16v o0, o1;
    #pragma unroll
    for (int r = 0; r < 16; r++) { o0[r] = 0.f; o1[r] = 0.f; }
    float lsum = 0.f;

    // initial tile: 512 threads stage 16KB K + 16KB V in 2 rounds
    #pragma unroll
    for (int t = 0; t < 2; t++) {
        const int flat = t * 4096 + tid8;
        *(h8*)&k_sm[flat >> 6][flat & 63] = *(const h8*)(khead + flat);
        *(h8*)&vt_sm[flat >> 7][flat & 127] =
            *(const h8*)(vthead + (size_t)(flat >> 7) * LL + (flat & 127));
    }
    BAR();

    for (int it = 0; it < 16; ++it) {
        const int s1 = it * 128 + 128;
        const bool more = (s1 < LL);

        h8 kpre[2], vpre[2];
        if (more) {
            const _Float16* kg = khead + (size_t)s1 * DKK;
            #pragma unroll
            for (int t = 0; t < 2; t++) kpre[t] = *(const h8*)(kg + t * 4096 + tid8);
            #pragma unroll
            for (int t = 0; t < 2; t++) {
                const int flat = t * 4096 + tid8;
                vpre[t] = *(const h8*)(vthead + (size_t)(flat >> 7) * LL + s1 + (flat & 127));
            }
        }

        // scores transposed: sc[st2] = [32s x 32q], A=K tile, B=Q.
        // this wave only computes its s-half: st = sh*2 + st2
        f16v sc[2];
        #pragma unroll
        for (int st2 = 0; st2 < 2; st2++) {
            const int st = sh * 2 + st2;
            #pragma unroll
            for (int r = 0; r < 16; r++) sc[st2][r] = 0.f;
            #pragma unroll
            for (int kf = 0; kf < 4; kf++) {
                h8 kf8 = *(const h8*)&k_sm[st * 32 + rq][kf * 16 + kb];
                sc[st2] = __builtin_amdgcn_mfma_f32_32x32x16_f16(kf8, qa[kf], sc[st2], 0, 0, 0);
            }
        }

        // per sub-tile: exp2 -> pack quads -> half-wave swap -> PV MFMAs
        #pragma unroll
        for (int st2 = 0; st2 < 2; st2++) {
            const int st = sh * 2 + st2;
            float p[16];
            #pragma unroll
            for (int r = 0; r < 16; r++) {
                p[r] = __builtin_amdgcn_exp2f(sc[st2][r]);
                lsum += p[r];
            }
            unsigned own[4][2], part[4][2];
            #pragma unroll
            for (int g = 0; g < 4; g++) {
                own[g][0] = pack2h(p[4 * g],     p[4 * g + 1]);
                own[g][1] = pack2h(p[4 * g + 2], p[4 * g + 3]);
                part[g][0] = __shfl_xor(own[g][0], 32, 64);
                part[g][1] = __shfl_xor(own[g][1], 32, 64);
            }
            #pragma unroll
            for (int j = 0; j < 2; j++) {
                union { unsigned u[4]; h8 h; } pa;
                pa.u[0] = hi ? part[2 * j + 1][0] : own[2 * j][0];
                pa.u[1] = hi ? part[2 * j + 1][1] : own[2 * j][1];
                pa.u[2] = hi ? own[2 * j + 1][0]  : part[2 * j][0];
                pa.u[3] = hi ? own[2 * j + 1][1]  : part[2 * j][1];
                h8 b0 = *(const h8*)&vt_sm[rq][st * 32 + j * 16 + kb];
                h8 b1 = *(const h8*)&vt_sm[32 + rq][st * 32 + j * 16 + kb];
                o0 = __builtin_amdgcn_mfma_f32_32x32x16_f16(pa.h, b0, o0, 0, 0, 0);
                o1 = __builtin_amdgcn_mfma_f32_32x32x16_f16(pa.h, b1, o1, 0, 0, 0);
            }
        }

        BAR();
        if (more) {
            #pragma unroll
            for (int t = 0; t < 2; t++) {
                const int flat = t * 4096 + tid8;
                *(h8*)&k_sm[flat >> 6][flat & 63] = kpre[t];
            }
            #pragma unroll
            for (int t = 0; t < 2; t++) {
                const int flat = t * 4096 + tid8;
                *(h8*)&vt_sm[flat >> 7][flat & 127] = vpre[t];
            }
            BAR();
        }
    }

    // combine the two intra-wave half partial sums for each q
    lsum += __shfl_xor(lsum, 32, 64);

    // cross-wave-pair combine: upper s-half waves publish (O, lsum) via LDS
    // (safe: the loop's final BAR guarantees all ds_reads of k/vt are done)
    float* myx = xch + ((qstrip * 64 + lane) * 33);   // stride 33 -> no bank conflict
    if (sh) {
        #pragma unroll
        for (int r = 0; r < 16; r++) { myx[r] = o0[r]; myx[16 + r] = o1[r]; }
        myx[32] = lsum;
    }
    BAR();
    if (!sh) {
        #pragma unroll
        for (int r = 0; r < 16; r++) { o0[r] += myx[r]; o1[r] += myx[16 + r]; }
        lsum += myx[32];
        ls_sm[wave][rq] = 1.0f / lsum;   // lanes L and L+32 write same value
        asm volatile("s_waitcnt lgkmcnt(0)" ::: "memory");

        // O layout: col = dk = lane&31, row = q = (r&3)+8*(r>>2)+4*hi
        const int b = head >> 4, h = head & 15;
        #pragma unroll
        for (int r = 0; r < 16; r++) {
            const int qrow = (r & 3) + 8 * (r >> 2) + 4 * hi;
            const float inv = ls_sm[wave][qrow];
            const int ql = qw + qrow;
            const size_t base = (size_t)(ql * BB + b) * DD + h * DKK;
            oh[base + rq]      = (_Float16)(o0[r] * inv);
            oh[base + 32 + rq] = (_Float16)(o1[r] * inv);
        }
    }
}

// ---------------------------------------------------------------------------
// Kernel 3: output projection, m97 structure, 64x128 tiles (grid 512).
// ---------------------------------------------------------------------------
__global__ __launch_bounds__(256) void out_proj(
    const _Float16* __restrict__ oh, const _Float16* __restrict__ wo,
    const float* __restrict__ bo, float* __restrict__ out)
{
    __shared__ alignas(16) _Float16 a_sm[64 * 32];
    __shared__ alignas(16) _Float16 b_sm[128 * 32];
    const int tid = threadIdx.x, lane = tid & 63, wave = tid >> 6;
    const int wm = (wave & 1) * 32, wn = (wave >> 1) * 64;
    const int m0 = blockIdx.x * 64, n0 = blockIdx.y * 128;

    const int srow = tid >> 2;
    const int scol = (tid & 3) * 8;
    const int lds_base = wave * 512;

    f4 acc[2][4];
    #pragma unroll
    for (int i = 0; i < 2; i++)
        #pragma unroll
        for (int j = 0; j < 4; j++)
            #pragma unroll
            for (int r = 0; r < 4; r++) acc[i][j][r] = 0.f;

    const int fr = lane & 15;
    const int fk = (lane >> 4) * 8;

    for (int k0 = 0; k0 < DD; k0 += 32) {
        gload_lds16(oh + (size_t)(m0 + srow) * DD + k0 + scol,      &a_sm[lds_base]);
        gload_lds16(wo + (size_t)(n0 + srow) * DD + k0 + scol,      &b_sm[lds_base]);
        gload_lds16(wo + (size_t)(n0 + 64 + srow) * DD + k0 + scol, &b_sm[2048 + lds_base]);
        __syncthreads();
        h8 af[2], bfr[4];
        #pragma unroll
        for (int i = 0; i < 2; i++) af[i]  = *(const h8*)&a_sm[(wm + i * 16 + fr) * 32 + fk];
        #pragma unroll
        for (int j = 0; j < 4; j++) bfr[j] = *(const h8*)&b_sm[(wn + j * 16 + fr) * 32 + fk];
        #pragma unroll
        for (int i = 0; i < 2; i++)
            #pragma unroll
            for (int j = 0; j < 4; j++)
                acc[i][j] = __builtin_amdgcn_mfma_f32_16x16x32_f16(af[i], bfr[j], acc[i][j], 0, 0, 0);
        __syncthreads();
    }

    const int colc = lane & 15;
    const int rowb = (lane >> 4) * 4;
    #pragma unroll
    for (int i = 0; i < 2; i++) {
        #pragma unroll
        for (int j = 0; j < 4; j++) {
            const int nn = n0 + wn + j * 16 + colc;
            const float bval = bo[nn];
            #pragma unroll
            for (int reg = 0; reg < 4; reg++) {
                const int mm = m0 + wm + i * 16 + rowb + reg;
                out[(size_t)mm * DD + nn] = acc[i][j][reg] + bval;
            }
        }
    }
}

extern "C" void kernel_launch(void* const* d_in, const int* in_sizes, int n_in,
                              void* d_out, int out_size, void* d_ws, size_t ws_size,
                              hipStream_t stream) {
    const float* qin = (const float*)d_in[0];
    const float* kin = (const float*)d_in[1];
    const float* vin = (const float*)d_in[2];
    const float* wq  = (const float*)d_in[3];
    const float* bq  = (const float*)d_in[4];
    const float* wk  = (const float*)d_in[5];
    const float* bk  = (const float*)d_in[6];
    const float* wv  = (const float*)d_in[7];
    const float* bv  = (const float*)d_in[8];
    const float* wo  = (const float*)d_in[9];
    const float* bo  = (const float*)d_in[10];

    const size_t seg = (size_t)32 * LL * DKK;  // 4,194,304 halves
    _Float16* qh  = (_Float16*)d_ws;
    _Float16* kh  = qh + seg;
    _Float16* vth = kh + seg;
    _Float16* oh  = vth + seg;
    _Float16* wqh = oh + seg;
    _Float16* wkh = wqh + (size_t)DD * DD;
    _Float16* wvh = wkh + (size_t)DD * DD;
    _Float16* woh = wvh + (size_t)DD * DD;
    _Float16* xqh = woh + (size_t)DD * DD;
    _Float16* xkh = xqh + seg;
    _Float16* xvh = xkh + seg;

    hipLaunchKernelGGL(cvt_all, dim3(2048, 7), dim3(256), 0, stream,
                       qin, kin, vin, wq, wk, wv, wo,
                       xqh, xkh, xvh, wqh, wkh, wvh, woh);
    hipLaunchKernelGGL(qkv_proj, dim3(32, 8, 3), dim3(256), 0, stream,
                       xqh, xkh, xvh, wqh, bq, wkh, bk, wvh, bv, qh, kh, vth);
    hipLaunchKernelGGL(attn, dim3(16, 32), dim3(512), 0, stream, qh, kh, vth, oh);
    hipLaunchKernelGGL(out_proj, dim3(64, 8), dim3(256), 0, stream, oh, woh,
                       bo, (float*)d_out);
}

// Round 2
// 218.989 us; speedup vs baseline: 1.0317x; 1.0317x over previous
//
#include <hip/hip_runtime.h>
#include <hip/hip_fp16.h>

#define LL 2048
#define BB 2
#define DD 1024
#define HH 16
#define DKK 64

typedef _Float16 h8 __attribute__((ext_vector_type(8)));
typedef _Float16 h4 __attribute__((ext_vector_type(4)));
typedef float f4 __attribute__((ext_vector_type(4)));
typedef float f16v __attribute__((ext_vector_type(16)));

// lgkm-only barrier (keeps prefetch global loads in flight across it)
#define BAR() do {                                              \
    asm volatile("s_waitcnt lgkmcnt(0)" ::: "memory");          \
    __builtin_amdgcn_s_barrier();                               \
    asm volatile("" ::: "memory");                              \
} while (0)

// async global->LDS, 16B per lane; LDS dest is wave-uniform base + lane*16
__device__ __forceinline__ void gload_lds16(const void* g, void* l) {
    __builtin_amdgcn_global_load_lds(
        (const __attribute__((address_space(1))) void*)g,
        (__attribute__((address_space(3))) void*)l, 16, 0, 0);
}

__device__ __forceinline__ unsigned pack2h(float a, float b) {
    union { _Float16 h[2]; unsigned u; } x;
    x.h[0] = (_Float16)a; x.h[1] = (_Float16)b;
    return x.u;
}

// ---------------------------------------------------------------------------
// Kernel 0: convert 7 arrays f32->f16: qin/kin/vin (4M each), wq/wk/wv/wo (1M).
// ---------------------------------------------------------------------------
__global__ __launch_bounds__(256) void cvt_all(
    const float* __restrict__ x0, const float* __restrict__ x1,
    const float* __restrict__ x2, const float* __restrict__ w0,
    const float* __restrict__ w1, const float* __restrict__ w2,
    const float* __restrict__ w3,
    _Float16* __restrict__ y0, _Float16* __restrict__ y1,
    _Float16* __restrict__ y2, _Float16* __restrict__ z0,
    _Float16* __restrict__ z1, _Float16* __restrict__ z2,
    _Float16* __restrict__ z3)
{
    const int sel = blockIdx.y;
    if (sel >= 3 && blockIdx.x >= 512) return;
    const float* src = (sel == 0) ? x0 : (sel == 1) ? x1 : (sel == 2) ? x2
                     : (sel == 3) ? w0 : (sel == 4) ? w1 : (sel == 5) ? w2 : w3;
    _Float16* dst = (sel == 0) ? y0 : (sel == 1) ? y1 : (sel == 2) ? y2
                  : (sel == 3) ? z0 : (sel == 4) ? z1 : (sel == 5) ? z2 : z3;
    const int i = (blockIdx.x * 256 + threadIdx.x) * 8;
    f4 a = *(const f4*)(src + i);
    f4 b = *(const f4*)(src + i + 4);
    h8 o = {(_Float16)a.x, (_Float16)a.y, (_Float16)a.z, (_Float16)a.w,
            (_Float16)b.x, (_Float16)b.y, (_Float16)b.z, (_Float16)b.w};
    *(h8*)(dst + i) = o;
}

// ---------------------------------------------------------------------------
// Kernel 1: QKV projections, m97 structure (global_load_lds + unpadded LDS).
//   mode 0: Q -> qh[head][l][dk] * (0.125 * log2e)   [attn uses exp2]
//   mode 1: K -> kh[head][l][dk]
//   mode 2: V -> vth[head][dk][l]
// ---------------------------------------------------------------------------
__global__ __launch_bounds__(256) void qkv_proj(
    const _Float16* __restrict__ xq, const _Float16* __restrict__ xk,
    const _Float16* __restrict__ xv,
    const _Float16* __restrict__ wq, const float* __restrict__ bq,
    const _Float16* __restrict__ wk, const float* __restrict__ bk,
    const _Float16* __restrict__ wv, const float* __restrict__ bv,
    _Float16* __restrict__ qh, _Float16* __restrict__ kh,
    _Float16* __restrict__ vth)
{
    const int mode = blockIdx.z;
    const _Float16* X    = (mode == 0) ? xq : (mode == 1) ? xk : xv;
    const _Float16* W    = (mode == 0) ? wq : (mode == 1) ? wk : wv;
    const float*    bias = (mode == 0) ? bq : (mode == 1) ? bk : bv;

    __shared__ alignas(16) _Float16 a_sm[128 * 32];
    __shared__ alignas(16) _Float16 b_sm[128 * 32];

    const int tid  = threadIdx.x;
    const int lane = tid & 63;
    const int wave = tid >> 6;
    const int wm = (wave & 1) * 64;
    const int wn = (wave >> 1) * 64;
    const int m0 = blockIdx.x * 128;
    const int n0 = blockIdx.y * 128;

    const int srow = tid >> 2;
    const int scol = (tid & 3) * 8;
    const int lds_base = wave * 512;

    f4 acc[4][4];
    #pragma unroll
    for (int i = 0; i < 4; i++)
        #pragma unroll
        for (int j = 0; j < 4; j++)
            #pragma unroll
            for (int r = 0; r < 4; r++) acc[i][j][r] = 0.f;

    const int fr = lane & 15;
    const int fk = (lane >> 4) * 8;

    for (int k0 = 0; k0 < DD; k0 += 32) {
        gload_lds16(X + (size_t)(m0 + srow) * DD + k0 + scol,       &a_sm[lds_base]);
        gload_lds16(X + (size_t)(m0 + 64 + srow) * DD + k0 + scol,  &a_sm[2048 + lds_base]);
        gload_lds16(W + (size_t)(n0 + srow) * DD + k0 + scol,       &b_sm[lds_base]);
        gload_lds16(W + (size_t)(n0 + 64 + srow) * DD + k0 + scol,  &b_sm[2048 + lds_base]);
        __syncthreads();
        h8 af[4], bfr[4];
        #pragma unroll
        for (int i = 0; i < 4; i++) af[i]  = *(const h8*)&a_sm[(wm + i * 16 + fr) * 32 + fk];
        #pragma unroll
        for (int j = 0; j < 4; j++) bfr[j] = *(const h8*)&b_sm[(wn + j * 16 + fr) * 32 + fk];
        #pragma unroll
        for (int i = 0; i < 4; i++)
            #pragma unroll
            for (int j = 0; j < 4; j++)
                acc[i][j] = __builtin_amdgcn_mfma_f32_16x16x32_f16(af[i], bfr[j], acc[i][j], 0, 0, 0);
        __syncthreads();
    }

    const int colc = lane & 15;
    const int rowb = (lane >> 4) * 4;
    #pragma unroll
    for (int i = 0; i < 4; i++) {
        #pragma unroll
        for (int j = 0; j < 4; j++) {
            const int nn = n0 + wn + j * 16 + colc;
            const float bval = bias[nn];
            #pragma unroll
            for (int reg = 0; reg < 4; reg++) {
                const int mm = m0 + wm + i * 16 + rowb + reg;
                float v = acc[i][j][reg] + bval;
                const int b = mm & 1, l = mm >> 1;
                const int h = nn >> 6, dk = nn & 63;
                const int head = b * HH + h;
                if (mode == 0) {
                    v *= 0.1803368801111243f;  // DK^-0.5 * log2(e)
                    qh[((size_t)head * LL + l) * DKK + dk] = (_Float16)v;
                } else if (mode == 1) {
                    kh[((size_t)head * LL + l) * DKK + dk] = (_Float16)v;
                } else {
                    vth[((size_t)head * DKK + dk) * LL + l] = (_Float16)v;
                }
            }
        }
    }
}

// ---------------------------------------------------------------------------
// Kernel 2: attention v5 — DMA double-buffer, 1 barrier/iter, permlane swap.
//   8 waves: (qstrip = wave&3) x (s-half = wave>>2).  Per 128-s tile:
//   K 16KB + V 16KB staged by global_load_lds into buf[it&1] (64KB total,
//   2 blocks/CU).  Linear LDS dest + inverse-XOR-swizzled global source +
//   XOR-swizzled ds_read (16B-chunk key = row&7): each 8-lane group's
//   ds_read_b128 spans all 32 banks -> conflict-free.
//   P-fragment half-wave exchange via v_permlane32_swap_b32 (replaces
//   16 shfl_xor + 16 cndmask per iter; no DS traffic, no lgkm waits).
// ---------------------------------------------------------------------------
__global__ __launch_bounds__(512, 4) void attn(
    const _Float16* __restrict__ qh, const _Float16* __restrict__ kh,
    const _Float16* __restrict__ vth, _Float16* __restrict__ oh)
{
    // bijective XCD swizzle: rb%8 (the XCD) selects a contiguous 4-head chunk
    const int rb = blockIdx.y * 16 + blockIdx.x;     // 0..511
    const int lb = (rb & 7) * 64 + (rb >> 3);        // bijection on [0,512)
    const int head = lb >> 4;
    const int q0   = (lb & 15) * 128;

    const int tid = threadIdx.x, lane = tid & 63, wave = tid >> 6;  // 0..7
    const int qstrip = wave & 3;
    const int sh     = wave >> 2;      // s-half of the tile this wave owns
    const int qw = q0 + qstrip * 32;

    // 2 x {K 16KB, V 16KB} double buffer = 64KB
    __shared__ alignas(16) char smem[65536];

    const int rq = lane & 31;
    const int hi = lane >> 5;
    const int kb = hi * 8;
    const unsigned key = (unsigned)(rq & 7);   // XOR swizzle key for reads

    const _Float16* khead  = kh  + (size_t)head * LL * DKK;
    const _Float16* vthead = vth + (size_t)head * DKK * LL;

    // ---- DMA stage of one 128-s tile (K: 128x8 chunks16, V: 64x16 chunks16)
    // this wave stages segments wave*2, wave*2+1 of each (1KB per gload)
    const int seg0 = wave * 2;
    auto stage = [&](int s0, unsigned koff, unsigned voff) {
        #pragma unroll
        for (int t = 0; t < 2; t++) {
            const int i = (seg0 + t) * 64 + lane;
            const int r = i >> 3, p = i & 7;
            gload_lds16(khead + (size_t)(s0 + r) * DKK + ((p ^ (r & 7)) << 3),
                        smem + koff + (unsigned)(seg0 + t) * 1024u);
        }
        #pragma unroll
        for (int t = 0; t < 2; t++) {
            const int i = (seg0 + t) * 64 + lane;
            const int r = i >> 4, p = i & 15;
            gload_lds16(vthead + (size_t)r * LL + s0 + ((p ^ (r & 7)) << 3),
                        smem + voff + (unsigned)(seg0 + t) * 1024u);
        }
    };

    // prologue: stage tile 0 into buffer A, load Q while it flies
    stage(0, 0u, 16384u);

    // Q strip 32x64 -> 4 B-frags: B[n=lane&31][k=hi*8+j]
    const _Float16* qbase = qh + ((size_t)head * LL + qw + rq) * DKK;
    h8 qa[4];
    #pragma unroll
    for (int kf = 0; kf < 4; kf++) qa[kf] = *(const h8*)(qbase + kf * 16 + kb);

    f16v o0, o1;
    #pragma unroll
    for (int r = 0; r < 16; r++) { o0[r] = 0.f; o1[r] = 0.f; }
    float lsum = 0.f;

    asm volatile("s_waitcnt vmcnt(0)" ::: "memory");
    BAR();

    for (int it = 0; it < 16; ++it) {
        const unsigned cb = (unsigned)(it & 1) * 32768u;         // current buf
        const unsigned nb = (unsigned)((it + 1) & 1) * 32768u;   // next buf
        if (it < 15) stage((it + 1) * 128, nb, nb + 16384u);

        const char* kc = smem + cb;            // K tile [128][8 chunks16]
        const char* vc = smem + cb + 16384u;   // V tile [64][16 chunks16]

        // scores transposed: sc[st2] = [32s x 32q], A=K tile, B=Q.
        f16v sc[2];
        #pragma unroll
        for (int st2 = 0; st2 < 2; st2++) {
            const int st = sh * 2 + st2;
            #pragma unroll
            for (int r = 0; r < 16; r++) sc[st2][r] = 0.f;
            #pragma unroll
            for (int kf = 0; kf < 4; kf++) {
                // K[s=st*32+rq][dk chunk kf*2+hi], swizzled
                h8 kf8 = *(const h8*)(kc +
                    ((((unsigned)(st * 32 + rq) << 3) +
                      (((unsigned)(kf * 2 + hi)) ^ key)) << 4));
                sc[st2] = __builtin_amdgcn_mfma_f32_32x32x16_f16(kf8, qa[kf], sc[st2], 0, 0, 0);
            }
        }

        // per sub-tile: exp2 -> pack pairs -> permlane32_swap -> PV MFMAs
        #pragma unroll
        for (int st2 = 0; st2 < 2; st2++) {
            const int st = sh * 2 + st2;
            float p[16];
            #pragma unroll
            for (int r = 0; r < 16; r++) {
                p[r] = __builtin_amdgcn_exp2f(sc[st2][r]);
                lsum += p[r];
            }
            unsigned w0[4], w1[4];
            #pragma unroll
            for (int g = 0; g < 4; g++) {
                w0[g] = pack2h(p[4 * g],     p[4 * g + 1]);
                w1[g] = pack2h(p[4 * g + 2], p[4 * g + 3]);
            }
            #pragma unroll
            for (int j = 0; j < 2; j++) {
                unsigned x0 = w0[2 * j], y0 = w0[2 * j + 1];
                unsigned x1 = w1[2 * j], y1 = w1[2 * j + 1];
                // after swap: x lo=own[2j], x hi=partner own[2j+1] (lo half);
                //             y lo=partner own[2j], y hi=own[2j+1]
                asm("v_permlane32_swap_b32 %0, %1" : "+v"(x0), "+v"(y0));
                asm("v_permlane32_swap_b32 %0, %1" : "+v"(x1), "+v"(y1));
                union { unsigned u[4]; h8 h; } pa;
                pa.u[0] = x0; pa.u[1] = x1; pa.u[2] = y0; pa.u[3] = y1;
                // V^T[dk=row][s chunk st*4+j*2+hi], swizzled; rows rq, rq+32
                h8 b0 = *(const h8*)(vc +
                    ((((unsigned)rq << 4) +
                      (((unsigned)(st * 4 + j * 2 + hi)) ^ key)) << 4));
                h8 b1 = *(const h8*)(vc +
                    ((((unsigned)(32 + rq) << 4) +
                      (((unsigned)(st * 4 + j * 2 + hi)) ^ key)) << 4));
                o0 = __builtin_amdgcn_mfma_f32_32x32x16_f16(pa.h, b0, o0, 0, 0, 0);
                o1 = __builtin_amdgcn_mfma_f32_32x32x16_f16(pa.h, b1, o1, 0, 0, 0);
            }
        }

        asm volatile("s_waitcnt vmcnt(0)" ::: "memory");  // next tile landed
        BAR();   // all waves done reading cur; nxt visible to all
    }

    // combine the two intra-wave half partial sums for each q
    lsum += __shfl_xor(lsum, 32, 64);

    // cross-wave-pair combine: upper s-half waves publish (O, lsum) via LDS
    float* xch = (float*)smem;                       // overlay (33,792B)
    float* lsp = (float*)(smem + 40960);             // [4][32] overlay
    float* myx = xch + ((qstrip * 64 + lane) * 33);  // stride 33: no conflicts
    if (sh) {
        #pragma unroll
        for (int r = 0; r < 16; r++) { myx[r] = o0[r]; myx[16 + r] = o1[r]; }
        myx[32] = lsum;
    }
    BAR();
    if (!sh) {
        #pragma unroll
        for (int r = 0; r < 16; r++) { o0[r] += myx[r]; o1[r] += myx[16 + r]; }
        lsum += myx[32];
        lsp[qstrip * 32 + rq] = 1.0f / lsum;   // lanes L, L+32 write same value
        asm volatile("s_waitcnt lgkmcnt(0)" ::: "memory");

        // O layout: col = dk = lane&31, row = q = (r&3)+8*(r>>2)+4*hi
        const int b = head >> 4, h = head & 15;
        #pragma unroll
        for (int r = 0; r < 16; r++) {
            const int qrow = (r & 3) + 8 * (r >> 2) + 4 * hi;
            const float inv = lsp[qstrip * 32 + qrow];
            const int ql = qw + qrow;
            const size_t base = (size_t)(ql * BB + b) * DD + h * DKK;
            oh[base + rq]      = (_Float16)(o0[r] * inv);
            oh[base + 32 + rq] = (_Float16)(o1[r] * inv);
        }
    }
}

// ---------------------------------------------------------------------------
// Kernel 3: output projection, m97 structure, 64x128 tiles (grid 512).
// ---------------------------------------------------------------------------
__global__ __launch_bounds__(256) void out_proj(
    const _Float16* __restrict__ oh, const _Float16* __restrict__ wo,
    const float* __restrict__ bo, float* __restrict__ out)
{
    __shared__ alignas(16) _Float16 a_sm[64 * 32];
    __shared__ alignas(16) _Float16 b_sm[128 * 32];
    const int tid = threadIdx.x, lane = tid & 63, wave = tid >> 6;
    const int wm = (wave & 1) * 32, wn = (wave >> 1) * 64;
    const int m0 = blockIdx.x * 64, n0 = blockIdx.y * 128;

    const int srow = tid >> 2;
    const int scol = (tid & 3) * 8;
    const int lds_base = wave * 512;

    f4 acc[2][4];
    #pragma unroll
    for (int i = 0; i < 2; i++)
        #pragma unroll
        for (int j = 0; j < 4; j++)
            #pragma unroll
            for (int r = 0; r < 4; r++) acc[i][j][r] = 0.f;

    const int fr = lane & 15;
    const int fk = (lane >> 4) * 8;

    for (int k0 = 0; k0 < DD; k0 += 32) {
        gload_lds16(oh + (size_t)(m0 + srow) * DD + k0 + scol,      &a_sm[lds_base]);
        gload_lds16(wo + (size_t)(n0 + srow) * DD + k0 + scol,      &b_sm[lds_base]);
        gload_lds16(wo + (size_t)(n0 + 64 + srow) * DD + k0 + scol, &b_sm[2048 + lds_base]);
        __syncthreads();
        h8 af[2], bfr[4];
        #pragma unroll
        for (int i = 0; i < 2; i++) af[i]  = *(const h8*)&a_sm[(wm + i * 16 + fr) * 32 + fk];
        #pragma unroll
        for (int j = 0; j < 4; j++) bfr[j] = *(const h8*)&b_sm[(wn + j * 16 + fr) * 32 + fk];
        #pragma unroll
        for (int i = 0; i < 2; i++)
            #pragma unroll
            for (int j = 0; j < 4; j++)
                acc[i][j] = __builtin_amdgcn_mfma_f32_16x16x32_f16(af[i], bfr[j], acc[i][j], 0, 0, 0);
        __syncthreads();
    }

    const int colc = lane & 15;
    const int rowb = (lane >> 4) * 4;
    #pragma unroll
    for (int i = 0; i < 2; i++) {
        #pragma unroll
        for (int j = 0; j < 4; j++) {
            const int nn = n0 + wn + j * 16 + colc;
            const float bval = bo[nn];
            #pragma unroll
            for (int reg = 0; reg < 4; reg++) {
                const int mm = m0 + wm + i * 16 + rowb + reg;
                out[(size_t)mm * DD + nn] = acc[i][j][reg] + bval;
            }
        }
    }
}

extern "C" void kernel_launch(void* const* d_in, const int* in_sizes, int n_in,
                              void* d_out, int out_size, void* d_ws, size_t ws_size,
                              hipStream_t stream) {
    const float* qin = (const float*)d_in[0];
    const float* kin = (const float*)d_in[1];
    const float* vin = (const float*)d_in[2];
    const float* wq  = (const float*)d_in[3];
    const float* bq  = (const float*)d_in[4];
    const float* wk  = (const float*)d_in[5];
    const float* bk  = (const float*)d_in[6];
    const float* wv  = (const float*)d_in[7];
    const float* bv  = (const float*)d_in[8];
    const float* wo  = (const float*)d_in[9];
    const float* bo  = (const float*)d_in[10];

    const size_t seg = (size_t)32 * LL * DKK;  // 4,194,304 halves
    _Float16* qh  = (_Float16*)d_ws;
    _Float16* kh  = qh + seg;
    _Float16* vth = kh + seg;
    _Float16* oh  = vth + seg;
    _Float16* wqh = oh + seg;
    _Float16* wkh = wqh + (size_t)DD * DD;
    _Float16* wvh = wkh + (size_t)DD * DD;
    _Float16* woh = wvh + (size_t)DD * DD;
    _Float16* xqh = woh + (size_t)DD * DD;
    _Float16* xkh = xqh + seg;
    _Float16* xvh = xkh + seg;

    hipLaunchKernelGGL(cvt_all, dim3(2048, 7), dim3(256), 0, stream,
                       qin, kin, vin, wq, wk, wv, wo,
                       xqh, xkh, xvh, wqh, wkh, wvh, woh);
    hipLaunchKernelGGL(qkv_proj, dim3(32, 8, 3), dim3(256), 0, stream,
                       xqh, xkh, xvh, wqh, bq, wkh, bk, wvh, bv, qh, kh, vth);
    hipLaunchKernelGGL(attn, dim3(16, 32), dim3(512), 0, stream, qh, kh, vth, oh);
    hipLaunchKernelGGL(out_proj, dim3(64, 8), dim3(256), 0, stream, oh, woh,
                       bo, (float*)d_out);
}